// Round 6
// baseline (305.656 us; speedup 1.0000x reference)
//
#include <hip/hip_runtime.h>

typedef unsigned short u16;
typedef __bf16 bf16x8 __attribute__((ext_vector_type(8)));
typedef __bf16 bf16x4 __attribute__((ext_vector_type(4)));
typedef float f32x4 __attribute__((ext_vector_type(4)));

#if __has_builtin(__builtin_amdgcn_exp2f)
#define EXP2(x) __builtin_amdgcn_exp2f(x)   // raw v_exp_f32 (inputs bounded, no denormal path)
#else
#define EXP2(x) exp2f(x)
#endif

template<int V> struct IC { static constexpr int val = V; };

// ---------- helpers ----------
__device__ __forceinline__ u16 f2bf(float f) {            // RNE fp32 -> bf16
    unsigned u = __float_as_uint(f);
    u += 0x7fffu + ((u >> 16) & 1u);
    return (u16)(u >> 16);
}

// async global->LDS, 16B per lane; LDS dest must be wave-uniform base (+lane*16 implicit)
__device__ __forceinline__ void gll16(const void* g, void* l) {
    __builtin_amdgcn_global_load_lds(
        (const __attribute__((address_space(1))) void*)g,
        (__attribute__((address_space(3))) void*)l, 16, 0, 0);
}

// ---------- fp32 -> bf16 conversion (vectorized, G13) ----------
__device__ __forceinline__ void cvt_body(const float* __restrict__ in,
                                         u16* __restrict__ out, int i) {
    float4 v = reinterpret_cast<const float4*>(in)[i];
    unsigned long long pack =
        (unsigned long long)f2bf(v.x) |
        ((unsigned long long)f2bf(v.y) << 16) |
        ((unsigned long long)f2bf(v.z) << 32) |
        ((unsigned long long)f2bf(v.w) << 48);
    reinterpret_cast<unsigned long long*>(out)[i] = pack;
}

// fused convert of the three big (B,S,H) tensors; grid covers 3*n4
__global__ __launch_bounds__(256) void cvt_bf16_3(const float* __restrict__ a,
                                                  const float* __restrict__ b,
                                                  const float* __restrict__ c,
                                                  u16* __restrict__ oa,
                                                  u16* __restrict__ ob,
                                                  u16* __restrict__ oc, int n4) {
    int i = blockIdx.x * 256 + threadIdx.x;
    if (i < n4)            cvt_body(a, oa, i);
    else if (i < 2 * n4)   cvt_body(b, ob, i - n4);
    else if (i < 3 * n4)   cvt_body(c, oc, i - 2 * n4);
}

// fused convert of the four HxH weights; grid covers 4*n4
__global__ __launch_bounds__(256) void cvt_bf16_w(const float* __restrict__ a,
                                                  const float* __restrict__ b,
                                                  const float* __restrict__ c,
                                                  const float* __restrict__ d,
                                                  u16* __restrict__ oa,
                                                  u16* __restrict__ ob,
                                                  u16* __restrict__ oc,
                                                  u16* __restrict__ od, int n4) {
    int i = blockIdx.x * 256 + threadIdx.x;
    if (i < n4)            cvt_body(a, oa, i);
    else if (i < 2 * n4)   cvt_body(b, ob, i - n4);
    else if (i < 3 * n4)   cvt_body(c, oc, i - 2 * n4);
    else if (i < 4 * n4)   cvt_body(d, od, i - 3 * n4);
}

// ---------- GEMM: C = A(M x K) @ B(N x K)^T, bf16 in, fp32 accum ----------
// (unchanged — passing since round 4)
template<int MODE>
__global__ __launch_bounds__(256) void gemm_bt(const u16* __restrict__ A,
                                               const u16* __restrict__ B,
                                               void* __restrict__ Cv,
                                               const float* __restrict__ bias) {
    constexpr int K = 1024, N = 1024;
    __shared__ __align__(16) u16 As[128 * 64];
    __shared__ __align__(16) u16 Bs[128 * 64];
    const int tid = threadIdx.x;
    const int wv = tid >> 6, lane = tid & 63, g = lane >> 4, li = lane & 15;
    const int row0 = blockIdx.y << 7, col0 = blockIdx.x << 7;
    const int wm = wv >> 1, wn = wv & 1;

    f32x4 acc[4][4] = {};

    for (int k0 = 0; k0 < K; k0 += 64) {
        __syncthreads();
#pragma unroll
        for (int i = 0; i < 4; i++) {       // A tile: 128 rows x 128B
            const int o   = (wv << 12) + (i << 10) + (lane << 4);
            const int row = o >> 7;
            const int cbg = (o & 127) ^ ((row & 7) << 4);
            gll16(A + (size_t)(row0 + row) * K + k0 + (cbg >> 1),
                  (char*)As + (wv << 12) + (i << 10));
        }
#pragma unroll
        for (int i = 0; i < 4; i++) {       // B tile (rows = output cols)
            const int o   = (wv << 12) + (i << 10) + (lane << 4);
            const int row = o >> 7;
            const int cbg = (o & 127) ^ ((row & 7) << 4);
            gll16(B + (size_t)(col0 + row) * K + k0 + (cbg >> 1),
                  (char*)Bs + (wv << 12) + (i << 10));
        }
        __syncthreads();

#pragma unroll
        for (int kk = 0; kk < 2; kk++) {
            bf16x8 af[4], bfr[4];
            const int cb = ((kk << 5) + (g << 3)) << 1;
#pragma unroll
            for (int m = 0; m < 4; m++) {
                const int row = (wm << 6) + (m << 4) + li;
                af[m] = *reinterpret_cast<const bf16x8*>(
                    (const char*)As + (row << 7) + (cb ^ ((row & 7) << 4)));
            }
#pragma unroll
            for (int n = 0; n < 4; n++) {
                const int row = (wn << 6) + (n << 4) + li;
                bfr[n] = *reinterpret_cast<const bf16x8*>(
                    (const char*)Bs + (row << 7) + (cb ^ ((row & 7) << 4)));
            }
#pragma unroll
            for (int m = 0; m < 4; m++)
#pragma unroll
                for (int n = 0; n < 4; n++)
                    acc[m][n] = __builtin_amdgcn_mfma_f32_16x16x32_bf16(
                        af[m], bfr[n], acc[m][n], 0, 0, 0);
        }
    }

    if constexpr (MODE == 0 || MODE == 3) {
        constexpr float SC = (MODE == 3) ? 0.180336880f : 1.0f;  // 1/8 * log2(e)
        u16* C = (u16*)Cv;
#pragma unroll
        for (int m = 0; m < 4; m++)
#pragma unroll
            for (int n = 0; n < 4; n++)
#pragma unroll
                for (int r = 0; r < 4; r++) {
                    int row = row0 + (wm << 6) + (m << 4) + (g << 2) + r;
                    int col = col0 + (wn << 6) + (n << 4) + li;
                    C[(size_t)row * N + col] = f2bf(acc[m][n][r] * SC);
                }
    } else if constexpr (MODE == 1) {
        float* C = (float*)Cv;
#pragma unroll
        for (int m = 0; m < 4; m++)
#pragma unroll
            for (int n = 0; n < 4; n++)
#pragma unroll
                for (int r = 0; r < 4; r++) {
                    int row = row0 + (wm << 6) + (m << 4) + (g << 2) + r;
                    int col = col0 + (wn << 6) + (n << 4) + li;
                    C[(size_t)row * N + col] = acc[m][n][r] + bias[col];
                }
    } else {  // MODE 2: V projection written per-head-transposed: (B,NH,DK,S)
        u16* C = (u16*)Cv;
#pragma unroll
        for (int m = 0; m < 4; m++)
#pragma unroll
            for (int n = 0; n < 4; n++) {
                int srow = row0 + (wm << 6) + (m << 4) + (g << 2);
                int col  = col0 + (wn << 6) + (n << 4) + li;
                int b = srow >> 11, s = srow & 2047;
                int nh = col >> 6, d = col & 63;
                unsigned long long pack =
                    (unsigned long long)f2bf(acc[m][n][0]) |
                    ((unsigned long long)f2bf(acc[m][n][1]) << 16) |
                    ((unsigned long long)f2bf(acc[m][n][2]) << 32) |
                    ((unsigned long long)f2bf(acc[m][n][3]) << 48);
                *reinterpret_cast<unsigned long long*>(
                    C + ((size_t)((b << 4) + nh) * 64 + d) * 2048 + s) = pack;
            }
    }
}

// ---------- flash attention (sigma-permuted PV: P stays in-lane) ----------
// 512 threads = 8 waves; block = (b, head, 128 q-rows); wave owns 16 q-rows.
// LDS = 32KB only: K dbuf [0,16K), V^T dbuf [16K,32K). Q is NOT staged (qf loaded
// directly from global, once). Swapped QK^T (mfma(K,Q)): lane (g,li) holds q-row
// wv*16+li, keys n*16+g*4+r in sc[n][r].
// PV uses a permuted MFMA k-ordering sigma(kk*32+g*8+i) = (2kk+(i>>2))*16+g*4+(i&3),
// applied to BOTH operands: A-frag = {sc[2kk],sc[2kk+1]} packed in-lane (NO LDS P!),
// B-frag = two b64 reads per (kk,n) from the V^T tile at the sigma'd key chunks.
// Maxless exp2 softmax (Q pre-scaled by 1/8*log2(e)).
// __launch_bounds__(512,8): VGPR<=64 -> 4 blocks/CU = 32 waves, grid 1024 = 1 round.
__global__ __launch_bounds__(512, 8) void attn_fwd(const u16* __restrict__ Q,
                                                   const u16* __restrict__ Kp,
                                                   const u16* __restrict__ Vt,
                                                   const int* __restrict__ mask,
                                                   u16* __restrict__ O) {
    constexpr int S = 2048, H = 1024;
    __shared__ __align__(16) char lds[32768];
    __shared__ int sm_bad;
    const int tid = threadIdx.x, wv = tid >> 6, lane = tid & 63;
    const int g = lane >> 4, li = lane & 15;
    const int q0 = blockIdx.x << 7, h = blockIdx.y, b = blockIdx.z;
    const char* Kg = (const char*)(Kp + (size_t)b * S * H + h * 64);
    const char* Vg = (const char*)(Vt + (size_t)(b * 16 + h) * 64 * S);

    // stage one 64-key K tile + V^T tile (8KB each; one gll16 per thread per tensor)
    auto stageKV = [&](int bufOff, int kv2) {
        const int o   = tid << 4;                          // 0..8191
        const int row = o >> 7;                            // 0..63
        const int cbg = (o & 127) ^ ((row & 7) << 4);      // pre-swizzled src col (bytes)
        gll16(Kg + (size_t)(kv2 + row) * 2048 + cbg, lds + bufOff + (wv << 10));
        gll16(Vg + (size_t)row * 4096 + kv2 * 2 + cbg, lds + 16384 + bufOff + (wv << 10));
    };

    if (tid == 0) sm_bad = 0;
    stageKV(0, 0);

    // Q fragments straight from global: lane (g,li) needs Q[q0+wv*16+li][kk*32+g*8..+8]
    bf16x8 qf[2];
    {
        const u16* Qrow = Q + (size_t)(b * S + q0 + (wv << 4) + li) * H + h * 64 + (g << 3);
        qf[0] = *reinterpret_cast<const bf16x8*>(Qrow);
        qf[1] = *reinterpret_cast<const bf16x8*>(Qrow + 32);
    }

    int z = 0;                                             // block mask scan, 4 keys/thread
#pragma unroll
    for (int j = 0; j < 4; j++) z |= (mask[b * S + (tid << 2) + j] == 0);
    __syncthreads();                                       // K0/V0 resident; sm_bad=0 visible
    if (z) sm_bad = 1;
    __syncthreads();
    const bool bad = (sm_bad != 0);
    const int  mq  = bad ? mask[b * S + q0 + (wv << 4) + li] : 1;

    // loop-invariant LDS byte offsets (within-tile; n adds a (n<<11) immediate)
    int offK[2], offV[2][2];
#pragma unroll
    for (int kk = 0; kk < 2; kk++) {
        offK[kk] = (li << 7) + (((kk << 6) + (g << 4)) ^ ((li & 7) << 4));
#pragma unroll
        for (int c = 0; c < 2; c++)
            offV[kk][c] = (li << 7) +
                          (((kk << 6) + (c << 5) + (g << 3)) ^ ((li & 7) << 4));
    }

    f32x4 o_[4] = {};
    float l_ = 0.f;

    // one 64-key tile; BUF compile-time so every LDS address is voff+imm
    auto tile = [&](auto BUF, int kv2) {
        constexpr int KOFF = decltype(BUF)::val * 8192;
        constexpr int VOFF = 16384 + decltype(BUF)::val * 8192;
        f32x4 sc[4] = {};
        __builtin_amdgcn_s_setprio(1);
#pragma unroll
        for (int kk = 0; kk < 2; kk++)
#pragma unroll
            for (int n = 0; n < 4; n++) {
                bf16x8 kf = *reinterpret_cast<const bf16x8*>(
                    lds + KOFF + offK[kk] + (n << 11));
                sc[n] = __builtin_amdgcn_mfma_f32_16x16x32_bf16(kf, qf[kk], sc[n], 0, 0, 0);
            }
        __builtin_amdgcn_s_setprio(0);

        if (bad) {
            const unsigned long long kb = __ballot(mask[b * S + kv2 + lane] != 0);
#pragma unroll
            for (int n = 0; n < 4; n++)
#pragma unroll
                for (int r = 0; r < 4; r++) {
                    const int key = (n << 4) + (g << 2) + r;
                    const bool ok = mq && ((kb >> key) & 1ull);
                    sc[n][r] = ok ? sc[n][r] : -1e9f;
                }
        }

        float rs = 0.f;                                    // maxless: p = exp2(s)
#pragma unroll
        for (int n = 0; n < 4; n++)
#pragma unroll
            for (int r = 0; r < 4; r++) {
                const float p = EXP2(sc[n][r]);
                sc[n][r] = p;
                rs += p;
            }
        rs += __shfl_xor(rs, 16);
        rs += __shfl_xor(rs, 32);
        l_ += rs;

        // sigma-pack: A-frag(kk) = {sc[2kk][0..3], sc[2kk+1][0..3]} — in-lane only
        bf16x8 pf0, pf1;
#pragma unroll
        for (int j = 0; j < 4; j++) {
            pf0[j]     = (__bf16)sc[0][j];
            pf0[4 + j] = (__bf16)sc[1][j];
            pf1[j]     = (__bf16)sc[2][j];
            pf1[4 + j] = (__bf16)sc[3][j];
        }

        __builtin_amdgcn_s_setprio(1);
#pragma unroll
        for (int kk = 0; kk < 2; kk++) {                   // O += P @ V (sigma'd k-order)
            const bf16x8 pf = kk ? pf1 : pf0;
#pragma unroll
            for (int n = 0; n < 4; n++) {
                bf16x4 v0 = *reinterpret_cast<const bf16x4*>(
                    lds + VOFF + offV[kk][0] + (n << 11));
                bf16x4 v1 = *reinterpret_cast<const bf16x4*>(
                    lds + VOFF + offV[kk][1] + (n << 11));
                bf16x8 vf;
#pragma unroll
                for (int j = 0; j < 4; j++) { vf[j] = v0[j]; vf[4 + j] = v1[j]; }
                o_[n] = __builtin_amdgcn_mfma_f32_16x16x32_bf16(pf, vf, o_[n], 0, 0, 0);
            }
        }
        __builtin_amdgcn_s_setprio(0);
    };

    for (int kv = 0; kv < S; kv += 128) {
        stageKV(8192, kv + 64);            // prefetch next tile (kv+64 <= 1984 always)
        tile(IC<0>{}, kv);
        __syncthreads();                   // buf0 reads done; buf1 staging drained
        if (kv + 128 < S) stageKV(0, kv + 128);
        tile(IC<1>{}, kv + 64);
        __syncthreads();                   // buf1 reads done; buf0 staging drained
    }

    // epilogue: l of q-row g*4+r lives in lane (lane&48)+(g<<2)+r of this wave
    float linv[4];
#pragma unroll
    for (int r = 0; r < 4; r++) {
        const float lr = __shfl(l_, (lane & 48) + (g << 2) + r);
        linv[r] = lr > 0.f ? 1.f / lr : 0.f;
    }
#pragma unroll
    for (int n = 0; n < 4; n++)
#pragma unroll
        for (int r = 0; r < 4; r++) {
            const int row = q0 + (wv << 4) + (g << 2) + r;
            const int col = (h << 6) + (n << 4) + li;
            O[(size_t)(b * S + row) * H + col] = f2bf(o_[n][r] * linv[r]);
        }
}

// ---------- launch ----------
extern "C" void kernel_launch(void* const* d_in, const int* in_sizes, int n_in,
                              void* d_out, int out_size, void* d_ws, size_t ws_size,
                              hipStream_t stream) {
    (void)in_sizes; (void)n_in; (void)out_size; (void)ws_size;
    const float* q    = (const float*)d_in[0];
    const float* k    = (const float*)d_in[1];
    const float* v    = (const float*)d_in[2];
    const int*   mask = (const int*)d_in[3];
    const float* Wq   = (const float*)d_in[4];
    const float* Wk   = (const float*)d_in[5];
    const float* Wv   = (const float*)d_in[6];
    const float* Wo   = (const float*)d_in[7];
    const float* bo   = (const float*)d_in[8];

    const size_t NEL = 8192ull * 1024ull;  // elements per (B,S,H) tensor
    u16* ws  = (u16*)d_ws;
    u16* r0  = ws;                       // q bf16  -> later K-proj
    u16* r1  = ws + NEL;                 // k bf16  -> later V^T
    u16* r2  = ws + 2 * NEL;             // v bf16  -> later attn out
    u16* wqb = ws + 3 * NEL;
    u16* wkb = wqb + 1024 * 1024;
    u16* wvb = wkb + 1024 * 1024;
    u16* wob = wvb + 1024 * 1024;
    u16* r4  = wob + 1024 * 1024;        // Q-proj (pre-scaled)

    const int n4 = (int)(NEL / 4);                 // 2,097,152 float4s per tensor
    const int cvt_blocks = (3 * n4 + 255) / 256;   // covers 3*n4
    cvt_bf16_3<<<dim3(cvt_blocks), dim3(256), 0, stream>>>(q, k, v, r0, r1, r2, n4);
    cvt_bf16_w<<<dim3(4096), dim3(256), 0, stream>>>(Wq, Wk, Wv, Wo,
                                                     wqb, wkb, wvb, wob, 262144);

    dim3 gg(8, 64), bb(256);
    gemm_bt<3><<<gg, bb, 0, stream>>>(r0, wqb, r4, nullptr);  // Q proj (scale folded)
    gemm_bt<0><<<gg, bb, 0, stream>>>(r1, wkb, r0, nullptr);  // K proj
    gemm_bt<2><<<gg, bb, 0, stream>>>(r2, wvb, r1, nullptr);  // V proj -> V^T layout

    attn_fwd<<<dim3(16, 16, 4), dim3(512), 0, stream>>>(r4, r0, r1, mask, r2);

    gemm_bt<1><<<gg, bb, 0, stream>>>(r2, wob, d_out, bo);    // out proj + bias
}

// Round 7
// 218.023 us; speedup vs baseline: 1.4019x; 1.4019x over previous
//
#include <hip/hip_runtime.h>

typedef unsigned short u16;
typedef __bf16 bf16x8 __attribute__((ext_vector_type(8)));
typedef __bf16 bf16x4 __attribute__((ext_vector_type(4)));
typedef float f32x4 __attribute__((ext_vector_type(4)));

#if __has_builtin(__builtin_amdgcn_exp2f)
#define EXP2(x) __builtin_amdgcn_exp2f(x)   // raw v_exp_f32 (inputs bounded, no denormal path)
#else
#define EXP2(x) exp2f(x)
#endif

template<int V> struct IC { static constexpr int val = V; };

// ---------- helpers ----------
__device__ __forceinline__ u16 f2bf(float f) {            // RNE fp32 -> bf16
    unsigned u = __float_as_uint(f);
    u += 0x7fffu + ((u >> 16) & 1u);
    return (u16)(u >> 16);
}

// async global->LDS, 16B per lane; LDS dest must be wave-uniform base (+lane*16 implicit)
__device__ __forceinline__ void gll16(const void* g, void* l) {
    __builtin_amdgcn_global_load_lds(
        (const __attribute__((address_space(1))) void*)g,
        (__attribute__((address_space(3))) void*)l, 16, 0, 0);
}

// ---------- fp32 -> bf16 conversion (vectorized, G13) ----------
__device__ __forceinline__ void cvt_body(const float* __restrict__ in,
                                         u16* __restrict__ out, int i) {
    float4 v = reinterpret_cast<const float4*>(in)[i];
    unsigned long long pack =
        (unsigned long long)f2bf(v.x) |
        ((unsigned long long)f2bf(v.y) << 16) |
        ((unsigned long long)f2bf(v.z) << 32) |
        ((unsigned long long)f2bf(v.w) << 48);
    reinterpret_cast<unsigned long long*>(out)[i] = pack;
}

// fused convert of the three big (B,S,H) tensors; grid covers 3*n4
__global__ __launch_bounds__(256) void cvt_bf16_3(const float* __restrict__ a,
                                                  const float* __restrict__ b,
                                                  const float* __restrict__ c,
                                                  u16* __restrict__ oa,
                                                  u16* __restrict__ ob,
                                                  u16* __restrict__ oc, int n4) {
    int i = blockIdx.x * 256 + threadIdx.x;
    if (i < n4)            cvt_body(a, oa, i);
    else if (i < 2 * n4)   cvt_body(b, ob, i - n4);
    else if (i < 3 * n4)   cvt_body(c, oc, i - 2 * n4);
}

// fused convert of the four HxH weights; grid covers 4*n4
__global__ __launch_bounds__(256) void cvt_bf16_w(const float* __restrict__ a,
                                                  const float* __restrict__ b,
                                                  const float* __restrict__ c,
                                                  const float* __restrict__ d,
                                                  u16* __restrict__ oa,
                                                  u16* __restrict__ ob,
                                                  u16* __restrict__ oc,
                                                  u16* __restrict__ od, int n4) {
    int i = blockIdx.x * 256 + threadIdx.x;
    if (i < n4)            cvt_body(a, oa, i);
    else if (i < 2 * n4)   cvt_body(b, ob, i - n4);
    else if (i < 3 * n4)   cvt_body(c, oc, i - 2 * n4);
    else if (i < 4 * n4)   cvt_body(d, od, i - 3 * n4);
}

// ---------- GEMM: C = A(M x K) @ B(N x K)^T, bf16 in, fp32 accum ----------
// (unchanged — passing since round 4)
template<int MODE>
__global__ __launch_bounds__(256) void gemm_bt(const u16* __restrict__ A,
                                               const u16* __restrict__ B,
                                               void* __restrict__ Cv,
                                               const float* __restrict__ bias) {
    constexpr int K = 1024, N = 1024;
    __shared__ __align__(16) u16 As[128 * 64];
    __shared__ __align__(16) u16 Bs[128 * 64];
    const int tid = threadIdx.x;
    const int wv = tid >> 6, lane = tid & 63, g = lane >> 4, li = lane & 15;
    const int row0 = blockIdx.y << 7, col0 = blockIdx.x << 7;
    const int wm = wv >> 1, wn = wv & 1;

    f32x4 acc[4][4] = {};

    for (int k0 = 0; k0 < K; k0 += 64) {
        __syncthreads();
#pragma unroll
        for (int i = 0; i < 4; i++) {       // A tile: 128 rows x 128B
            const int o   = (wv << 12) + (i << 10) + (lane << 4);
            const int row = o >> 7;
            const int cbg = (o & 127) ^ ((row & 7) << 4);
            gll16(A + (size_t)(row0 + row) * K + k0 + (cbg >> 1),
                  (char*)As + (wv << 12) + (i << 10));
        }
#pragma unroll
        for (int i = 0; i < 4; i++) {       // B tile (rows = output cols)
            const int o   = (wv << 12) + (i << 10) + (lane << 4);
            const int row = o >> 7;
            const int cbg = (o & 127) ^ ((row & 7) << 4);
            gll16(B + (size_t)(col0 + row) * K + k0 + (cbg >> 1),
                  (char*)Bs + (wv << 12) + (i << 10));
        }
        __syncthreads();

#pragma unroll
        for (int kk = 0; kk < 2; kk++) {
            bf16x8 af[4], bfr[4];
            const int cb = ((kk << 5) + (g << 3)) << 1;
#pragma unroll
            for (int m = 0; m < 4; m++) {
                const int row = (wm << 6) + (m << 4) + li;
                af[m] = *reinterpret_cast<const bf16x8*>(
                    (const char*)As + (row << 7) + (cb ^ ((row & 7) << 4)));
            }
#pragma unroll
            for (int n = 0; n < 4; n++) {
                const int row = (wn << 6) + (n << 4) + li;
                bfr[n] = *reinterpret_cast<const bf16x8*>(
                    (const char*)Bs + (row << 7) + (cb ^ ((row & 7) << 4)));
            }
#pragma unroll
            for (int m = 0; m < 4; m++)
#pragma unroll
                for (int n = 0; n < 4; n++)
                    acc[m][n] = __builtin_amdgcn_mfma_f32_16x16x32_bf16(
                        af[m], bfr[n], acc[m][n], 0, 0, 0);
        }
    }

    if constexpr (MODE == 0 || MODE == 3) {
        constexpr float SC = (MODE == 3) ? 0.180336880f : 1.0f;  // 1/8 * log2(e)
        u16* C = (u16*)Cv;
#pragma unroll
        for (int m = 0; m < 4; m++)
#pragma unroll
            for (int n = 0; n < 4; n++)
#pragma unroll
                for (int r = 0; r < 4; r++) {
                    int row = row0 + (wm << 6) + (m << 4) + (g << 2) + r;
                    int col = col0 + (wn << 6) + (n << 4) + li;
                    C[(size_t)row * N + col] = f2bf(acc[m][n][r] * SC);
                }
    } else if constexpr (MODE == 1) {
        float* C = (float*)Cv;
#pragma unroll
        for (int m = 0; m < 4; m++)
#pragma unroll
            for (int n = 0; n < 4; n++)
#pragma unroll
                for (int r = 0; r < 4; r++) {
                    int row = row0 + (wm << 6) + (m << 4) + (g << 2) + r;
                    int col = col0 + (wn << 6) + (n << 4) + li;
                    C[(size_t)row * N + col] = acc[m][n][r] + bias[col];
                }
    } else {  // MODE 2: V projection written per-head-transposed: (B,NH,DK,S)
        u16* C = (u16*)Cv;
#pragma unroll
        for (int m = 0; m < 4; m++)
#pragma unroll
            for (int n = 0; n < 4; n++) {
                int srow = row0 + (wm << 6) + (m << 4) + (g << 2);
                int col  = col0 + (wn << 6) + (n << 4) + li;
                int b = srow >> 11, s = srow & 2047;
                int nh = col >> 6, d = col & 63;
                unsigned long long pack =
                    (unsigned long long)f2bf(acc[m][n][0]) |
                    ((unsigned long long)f2bf(acc[m][n][1]) << 16) |
                    ((unsigned long long)f2bf(acc[m][n][2]) << 32) |
                    ((unsigned long long)f2bf(acc[m][n][3]) << 48);
                *reinterpret_cast<unsigned long long*>(
                    C + ((size_t)((b << 4) + nh) * 64 + d) * 2048 + s) = pack;
            }
    }
}

// ---------- flash attention (tau-permuted K rows, in-lane P, b128 PV) ----------
// 512 threads = 8 waves; block = (b, head, 128 q-rows); wave owns 16 q-rows.
// LDS = 32KB: K dbuf [0,16K), V^T dbuf [16K,32K). Q loaded straight from global.
// K staging permutes WHICH global key lands in each LDS row (per-lane source addr,
// free): LDS row pr = n*16+g*4+r holds global key tau(pr) = g*16+n*4+r.
// => after swapped QK^T (mfma(K,Q)), lane (g,li) holds q-row wv*16+li and the 16
// CONTIGUOUS keys g*16+{0..15}: sc[n][r] = key g*16+n*4+r.
// => PV A-frag(kk) = {sc[2kk],sc[2kk+1]} packed IN-LANE (keys g*16+kk*8+{0..7}),
//    B-frag = ONE b128 from naturally-ordered V^T tile at byte (g<<5)+(kk<<4).
// Maxless exp2 softmax (Q pre-scaled by 1/8*log2(e); scores bounded).
__global__ __launch_bounds__(512, 4) void attn_fwd(const u16* __restrict__ Q,
                                                   const u16* __restrict__ Kp,
                                                   const u16* __restrict__ Vt,
                                                   const int* __restrict__ mask,
                                                   u16* __restrict__ O) {
    constexpr int S = 2048, H = 1024;
    __shared__ __align__(16) char lds[32768];
    __shared__ int sm_bad;
    const int tid = threadIdx.x, wv = tid >> 6, lane = tid & 63;
    const int g = lane >> 4, li = lane & 15;
    const int q0 = blockIdx.x << 7, h = blockIdx.y, b = blockIdx.z;
    const char* Kg = (const char*)(Kp + (size_t)b * S * H + h * 64);
    const char* Vg = (const char*)(Vt + (size_t)(b * 16 + h) * 64 * S);

    // stage one 64-key K tile (rows tau-permuted) + V^T tile (natural key order)
    auto stageKV = [&](int bufOff, int kv2) {
        const int o   = tid << 4;                          // 0..8191
        const int row = o >> 7;                            // LDS row pr = n*16+g*4+r
        const int cbg = (o & 127) ^ ((row & 7) << 4);      // pre-swizzled src col (bytes)
        const int gk  = (((row >> 2) & 3) << 4) + ((row >> 4) << 2) + (row & 3); // tau(pr)
        gll16(Kg + (size_t)(kv2 + gk) * 2048 + cbg, lds + bufOff + (wv << 10));
        gll16(Vg + (size_t)row * 4096 + kv2 * 2 + cbg, lds + 16384 + bufOff + (wv << 10));
    };

    if (tid == 0) sm_bad = 0;
    stageKV(0, 0);

    // Q fragments straight from global: lane (g,li) needs Q[q0+wv*16+li][g*8 + kk*32 ..]
    bf16x8 qf[2];
    {
        const u16* Qrow = Q + (size_t)(b * S + q0 + (wv << 4) + li) * H + h * 64 + (g << 3);
        qf[0] = *reinterpret_cast<const bf16x8*>(Qrow);
        qf[1] = *reinterpret_cast<const bf16x8*>(Qrow + 32);
    }

    int z = 0;                                             // block mask scan, 4 keys/thread
#pragma unroll
    for (int j = 0; j < 4; j++) z |= (mask[b * S + (tid << 2) + j] == 0);
    __syncthreads();                                       // K0/V0 resident; sm_bad=0 visible
    if (z) sm_bad = 1;
    __syncthreads();
    const bool bad = (sm_bad != 0);
    const int  mq  = bad ? mask[b * S + q0 + (wv << 4) + li] : 1;

    // loop-invariant LDS byte offsets (within-tile; n adds a (n<<11) immediate)
    int offK[2], offV[2];
#pragma unroll
    for (int kk = 0; kk < 2; kk++) {
        offK[kk] = (li << 7) + (((kk << 6) + (g << 4)) ^ ((li & 7) << 4));  // k=dim chunk
        offV[kk] = (li << 7) + (((g << 5) + (kk << 4)) ^ ((li & 7) << 4));  // key chunk
    }

    f32x4 o_[4] = {};
    float l_ = 0.f;

    // one 64-key tile; BUF compile-time so every LDS address is voff+imm
    auto tile = [&](auto BUF, int kv2) {
        constexpr int KOFF = decltype(BUF)::val * 8192;
        constexpr int VOFF = 16384 + decltype(BUF)::val * 8192;
        f32x4 sc[4] = {};
        __builtin_amdgcn_s_setprio(1);
#pragma unroll
        for (int kk = 0; kk < 2; kk++)
#pragma unroll
            for (int n = 0; n < 4; n++) {
                bf16x8 kf = *reinterpret_cast<const bf16x8*>(
                    lds + KOFF + offK[kk] + (n << 11));
                sc[n] = __builtin_amdgcn_mfma_f32_16x16x32_bf16(kf, qf[kk], sc[n], 0, 0, 0);
            }
        __builtin_amdgcn_s_setprio(0);

        if (bad) {    // sc[n][r] is key kv2 + g*16 + n*4 + r (tau relabeling)
            const unsigned long long kb = __ballot(mask[b * S + kv2 + lane] != 0);
#pragma unroll
            for (int n = 0; n < 4; n++)
#pragma unroll
                for (int r = 0; r < 4; r++) {
                    const int key = (g << 4) + (n << 2) + r;
                    const bool ok = mq && ((kb >> key) & 1ull);
                    sc[n][r] = ok ? sc[n][r] : -1e9f;
                }
        }

        float rs = 0.f;                                    // maxless: p = exp2(s)
#pragma unroll
        for (int n = 0; n < 4; n++)
#pragma unroll
            for (int r = 0; r < 4; r++) {
                const float p = EXP2(sc[n][r]);
                sc[n][r] = p;
                rs += p;
            }
        rs += __shfl_xor(rs, 16);
        rs += __shfl_xor(rs, 32);
        l_ += rs;

        // A-frag pack: pf0 = keys g*16+{0..7}, pf1 = keys g*16+{8..15} — in-lane only
        bf16x8 pf0, pf1;
#pragma unroll
        for (int j = 0; j < 4; j++) {
            pf0[j]     = (__bf16)sc[0][j];
            pf0[4 + j] = (__bf16)sc[1][j];
            pf1[j]     = (__bf16)sc[2][j];
            pf1[4 + j] = (__bf16)sc[3][j];
        }

        __builtin_amdgcn_s_setprio(1);
#pragma unroll
        for (int kk = 0; kk < 2; kk++) {                   // O += P @ V (b128 B-frags)
            const bf16x8 pf = kk ? pf1 : pf0;
#pragma unroll
            for (int n = 0; n < 4; n++) {
                bf16x8 vf = *reinterpret_cast<const bf16x8*>(
                    lds + VOFF + offV[kk] + (n << 11));
                o_[n] = __builtin_amdgcn_mfma_f32_16x16x32_bf16(pf, vf, o_[n], 0, 0, 0);
            }
        }
        __builtin_amdgcn_s_setprio(0);
    };

    for (int kv = 0; kv < S; kv += 128) {
        stageKV(8192, kv + 64);            // prefetch next tile (kv+64 <= 1984 always)
        tile(IC<0>{}, kv);
        __syncthreads();                   // buf0 reads done; buf1 staging drained
        if (kv + 128 < S) stageKV(0, kv + 128);
        tile(IC<1>{}, kv + 64);
        __syncthreads();                   // buf1 reads done; buf0 staging drained
    }

    // epilogue: l of q-row g*4+r lives in lane (lane&48)+(g<<2)+r of this wave
    float linv[4];
#pragma unroll
    for (int r = 0; r < 4; r++) {
        const float lr = __shfl(l_, (lane & 48) + (g << 2) + r);
        linv[r] = lr > 0.f ? 1.f / lr : 0.f;
    }
#pragma unroll
    for (int n = 0; n < 4; n++)
#pragma unroll
        for (int r = 0; r < 4; r++) {
            const int row = q0 + (wv << 4) + (g << 2) + r;
            const int col = (h << 6) + (n << 4) + li;
            O[(size_t)(b * S + row) * H + col] = f2bf(o_[n][r] * linv[r]);
        }
}

// ---------- launch ----------
extern "C" void kernel_launch(void* const* d_in, const int* in_sizes, int n_in,
                              void* d_out, int out_size, void* d_ws, size_t ws_size,
                              hipStream_t stream) {
    (void)in_sizes; (void)n_in; (void)out_size; (void)ws_size;
    const float* q    = (const float*)d_in[0];
    const float* k    = (const float*)d_in[1];
    const float* v    = (const float*)d_in[2];
    const int*   mask = (const int*)d_in[3];
    const float* Wq   = (const float*)d_in[4];
    const float* Wk   = (const float*)d_in[5];
    const float* Wv   = (const float*)d_in[6];
    const float* Wo   = (const float*)d_in[7];
    const float* bo   = (const float*)d_in[8];

    const size_t NEL = 8192ull * 1024ull;  // elements per (B,S,H) tensor
    u16* ws  = (u16*)d_ws;
    u16* r0  = ws;                       // q bf16  -> later K-proj
    u16* r1  = ws + NEL;                 // k bf16  -> later V^T
    u16* r2  = ws + 2 * NEL;             // v bf16  -> later attn out
    u16* wqb = ws + 3 * NEL;
    u16* wkb = wqb + 1024 * 1024;
    u16* wvb = wkb + 1024 * 1024;
    u16* wob = wvb + 1024 * 1024;
    u16* r4  = wob + 1024 * 1024;        // Q-proj (pre-scaled)

    const int n4 = (int)(NEL / 4);                 // 2,097,152 float4s per tensor
    const int cvt_blocks = (3 * n4 + 255) / 256;   // covers 3*n4
    cvt_bf16_3<<<dim3(cvt_blocks), dim3(256), 0, stream>>>(q, k, v, r0, r1, r2, n4);
    cvt_bf16_w<<<dim3(4096), dim3(256), 0, stream>>>(Wq, Wk, Wv, Wo,
                                                     wqb, wkb, wvb, wob, 262144);

    dim3 gg(8, 64), bb(256);
    gemm_bt<3><<<gg, bb, 0, stream>>>(r0, wqb, r4, nullptr);  // Q proj (scale folded)
    gemm_bt<0><<<gg, bb, 0, stream>>>(r1, wkb, r0, nullptr);  // K proj
    gemm_bt<2><<<gg, bb, 0, stream>>>(r2, wvb, r1, nullptr);  // V proj -> V^T layout

    attn_fwd<<<dim3(16, 16, 4), dim3(512), 0, stream>>>(r4, r0, r1, mask, r2);

    gemm_bt<1><<<gg, bb, 0, stream>>>(r2, wob, d_out, bo);    // out proj + bias
}